// Round 2
// baseline (414.731 us; speedup 1.0000x reference)
//
#include <hip/hip_runtime.h>

// ---------- helpers ----------
typedef __attribute__((ext_vector_type(8))) short short8;
typedef __attribute__((ext_vector_type(4))) float f32x4;

__device__ __forceinline__ unsigned short f2bf(float f) {
    union { float f; unsigned u; } v; v.f = f;
    unsigned r = v.u + 0x7FFFu + ((v.u >> 16) & 1u);   // RNE
    return (unsigned short)(r >> 16);
}
__device__ __forceinline__ float bf2f(unsigned short h) {
    union { unsigned u; float f; } v; v.u = ((unsigned)h) << 16;
    return v.f;
}

// fast tanh: 1 v_exp_f32 + 1 v_rcp_f32. rel err ~1e-5 << bf16 ulp.
__device__ __forceinline__ float tanh_fast(float x) {
    float xc = fminf(fmaxf(x, -9.0f), 9.0f);
    float t  = __expf(2.0f * xc);
    return (t - 1.0f) * __builtin_amdgcn_rcpf(t + 1.0f);
}

__device__ __forceinline__ unsigned long long pack4(float4 v) {
    return (unsigned long long)f2bf(v.x)
         | ((unsigned long long)f2bf(v.y) << 16)
         | ((unsigned long long)f2bf(v.z) << 32)
         | ((unsigned long long)f2bf(v.w) << 48);
}

#define GLD16(gptr, lptr)                                                     \
    __builtin_amdgcn_global_load_lds(                                         \
        (const __attribute__((address_space(1))) unsigned int*)(gptr),        \
        (__attribute__((address_space(3))) unsigned int*)(lptr), 16, 0, 0)

// ---------- weight casts only: W1|W2|W3 f32 -> bf16 (x cast fused into MLP) ----------
__global__ __launch_bounds__(256) void cast_w(
    const float* __restrict__ W1, unsigned short* __restrict__ w1bf,
    const float* __restrict__ W2, unsigned short* __restrict__ w2bf,
    const float* __restrict__ W3, unsigned short* __restrict__ w3bf)
{
    int t = blockIdx.x * 256 + threadIdx.x;
    const float* s; unsigned short* d; int q;
    if (t < 32768)      { s = W1; d = w1bf; q = t; }
    else if (t < 65536) { s = W2; d = w2bf; q = t - 32768; }
    else if (t < 73728) { s = W3; d = w3bf; q = t - 65536; }
    else return;
    int base = q * 4;
    float4 v = *(const float4*)(s + base);
    *(unsigned long long*)(d + base) = pack4(v);
}

// ---------- fully fused MLP: h = (tanh(tanh(x@W1^T+b1)@W2^T+b2))@W3^T+b3 ----------
// Per block: 64 rows. x cast in-register -> xs (LDS); h1 (64x512) and h2 (64x256)
// live only in LDS; only h (64x128 bf16) hits HBM. 512 thr = 8 waves (2/SIMD),
// LDS 130 KB -> 1 block/CU.
__global__ __launch_bounds__(512, 2) void mlp_fused(
    const float* __restrict__ x,
    const unsigned short* __restrict__ W1, const float* __restrict__ b1,
    const unsigned short* __restrict__ W2, const float* __restrict__ b2,
    const unsigned short* __restrict__ W3, const float* __restrict__ b3,
    unsigned short* __restrict__ hout, int M)
{
    __shared__ __align__(16) short Bs[256][64];      // 32 KB  weight k-tiles (all phases)
    __shared__ __align__(16) short h1s[64][520];     // 66.5 KB (stride 520: 4r%32 bank shift -> 2-way=free)
    __shared__ __align__(16) short pool[64 * 264];   // 33 KB  xs (16384 shorts) then h2s (16896)

    const int tid  = threadIdx.x;
    const int wave = tid >> 6;                 // 0..7
    const int lane = tid & 63;
    const int m0   = blockIdx.x * 64;
    const int wm   = (wave >> 1) * 16;         // row group: 0/16/32/48
    const int half = wave & 1;                 // column-half selector
    const int lm   = lane & 15;
    const int quad = lane >> 4;
    const int srow = lane >> 3;
    const int scol = ((lane & 7) ^ srow) * 8;  // swizzled source col (shorts)
    const int cc0  = (quad ^ (lm & 7)) * 8;
    const int cc1  = ((4 + quad) ^ (lm & 7)) * 8;

    short (*xs)[64]   = (short(*)[64])pool;    // [4*64][64]: kt*64+row
    short (*h2s)[264] = (short(*)[264])pool;   // aliases xs (xs dead after phase 1)

    // ---- stage x f32 -> bf16 into xs (once; same lane->slot map as GLD16) ----
    {
        int gr = m0 + wave * 8 + srow; if (gr >= M) gr = M - 1;
        const float* xr = x + (size_t)gr * 256;
        #pragma unroll
        for (int kt = 0; kt < 4; ++kt) {
            float4 va = *(const float4*)(xr + kt * 64 + scol);
            float4 vb = *(const float4*)(xr + kt * 64 + scol + 4);
            unsigned long long* dp =
                (unsigned long long*)&xs[kt * 64 + wave * 8 + srow][(lane & 7) * 8];
            dp[0] = pack4(va); dp[1] = pack4(vb);
        }
    }
    // first __syncthreads below (phase-1 staging) covers the ds_writes

    // ---- phase 1: h1 = tanh(x @ W1^T + b1) -> h1s, two 256-col halves ----
    for (int nh = 0; nh < 2; ++nh) {
        f32x4 acc[8] = {};
        for (int kt = 0; kt < 4; ++kt) {
            #pragma unroll
            for (int i = 0; i < 4; ++i) {                      // 256 W1 rows
                int r0 = wave * 32 + i * 8;
                GLD16(W1 + (size_t)(nh * 256 + r0 + srow) * 256 + kt * 64 + scol, &Bs[r0][0]);
            }
            __syncthreads();
            #pragma unroll
            for (int ks = 0; ks < 2; ++ks) {
                const int cc = ks ? cc1 : cc0;
                short8 af = *(const short8*)&xs[kt * 64 + wm + lm][cc];
                #pragma unroll
                for (int in = 0; in < 8; ++in) {
                    short8 bv = *(const short8*)&Bs[half * 128 + in * 16 + lm][cc];
                    acc[in] = __builtin_amdgcn_mfma_f32_16x16x32_bf16(af, bv, acc[in], 0, 0, 0);
                }
            }
            __syncthreads();
        }
        int rb = wm + quad * 4;
        #pragma unroll
        for (int in = 0; in < 8; ++in) {
            int col = nh * 256 + half * 128 + in * 16 + lm;
            float bv = b1[col];
            #pragma unroll
            for (int r = 0; r < 4; ++r)
                h1s[rb + r][col] = (short)f2bf(tanh_fast(acc[in][r] + bv));
        }
    }
    __syncthreads();   // h1s complete (also: xs dead from here -> pool becomes h2s)

    // ---- phase 2: h2 = tanh(h1s @ W2^T + b2) -> h2s ----
    {
        f32x4 acc[8] = {};
        for (int k0 = 0; k0 < 512; k0 += 64) {
            #pragma unroll
            for (int i = 0; i < 4; ++i) {                      // 256 W2 rows
                int r0 = wave * 32 + i * 8;
                GLD16(W2 + (size_t)(r0 + srow) * 512 + k0 + scol, &Bs[r0][0]);
            }
            __syncthreads();
            #pragma unroll
            for (int ks = 0; ks < 2; ++ks) {
                const int cc = ks ? cc1 : cc0;
                short8 af = *(const short8*)&h1s[wm + lm][k0 + ks * 32 + quad * 8];
                #pragma unroll
                for (int in = 0; in < 8; ++in) {
                    short8 bv = *(const short8*)&Bs[half * 128 + in * 16 + lm][cc];
                    acc[in] = __builtin_amdgcn_mfma_f32_16x16x32_bf16(af, bv, acc[in], 0, 0, 0);
                }
            }
            __syncthreads();
        }
        int rb = wm + quad * 4;
        #pragma unroll
        for (int in = 0; in < 8; ++in) {
            int col = half * 128 + in * 16 + lm;
            float bv = b2[col];
            #pragma unroll
            for (int r = 0; r < 4; ++r)
                h2s[rb + r][col] = (short)f2bf(tanh_fast(acc[in][r] + bv));
        }
    }
    // no barrier needed here: phase-3 staging writes Bs (no readers), and the
    // staging barrier below orders all h2s writes before any h2s read.

    // ---- phase 3: h = h2s @ W3^T + b3 -> global bf16 ----
    {
        f32x4 acc[4] = {};
        for (int k0 = 0; k0 < 256; k0 += 64) {
            #pragma unroll
            for (int i = 0; i < 2; ++i) {                      // 128 W3 rows
                int r0 = wave * 16 + i * 8;
                GLD16(W3 + (size_t)(r0 + srow) * 256 + k0 + scol, &Bs[r0][0]);
            }
            __syncthreads();
            #pragma unroll
            for (int ks = 0; ks < 2; ++ks) {
                const int cc = ks ? cc1 : cc0;
                short8 af = *(const short8*)&h2s[wm + lm][k0 + ks * 32 + quad * 8];
                #pragma unroll
                for (int in = 0; in < 4; ++in) {
                    short8 bv = *(const short8*)&Bs[half * 64 + in * 16 + lm][cc];
                    acc[in] = __builtin_amdgcn_mfma_f32_16x16x32_bf16(af, bv, acc[in], 0, 0, 0);
                }
            }
            __syncthreads();
        }
        int gm_base = m0 + wm + quad * 4;
        #pragma unroll
        for (int in = 0; in < 4; ++in) {
            int gn = half * 64 + in * 16 + lm;
            float bv = b3[gn];
            #pragma unroll
            for (int r = 0; r < 4; ++r) {
                int gm = gm_base + r;
                if (gm < M)
                    hout[(size_t)gm * 128 + gn] = f2bf(acc[in][r] + bv);
            }
        }
    }
}

// ---------- edge histogram: packed (degAll<<32 | degGated) ----------
__global__ __launch_bounds__(256) void edge_hist(
    const int* __restrict__ ei, const float* __restrict__ alpha,
    unsigned long long* __restrict__ deg, int E)
{
    int e = blockIdx.x * 256 + threadIdx.x;
    if (e >= E) return;
    int dst = ei[E + e];
    float gate = 2.0f * fmaxf(alpha[e] - 0.5f, 0.0f);
    atomicAdd(&deg[dst], 0x100000000ULL | (gate > 0.0f ? 1ULL : 0ULL));
}

// ---------- scan step 1: per-block (1024) exclusive scan; writes rowptr+cursor ----------
__global__ __launch_bounds__(256) void scan1(
    const unsigned long long* __restrict__ deg, int* __restrict__ rowptr,
    int* __restrict__ cursor, int* __restrict__ partials, int N)
{
    __shared__ int sums[256];
    int base = blockIdx.x * 1024 + threadIdx.x * 4;
    int v[4];
    #pragma unroll
    for (int i = 0; i < 4; ++i) {
        int idx = base + i;
        v[i] = (idx < N) ? (int)(deg[idx] & 0xffffffffULL) : 0;
    }
    int s = v[0] + v[1] + v[2] + v[3];
    sums[threadIdx.x] = s;
    __syncthreads();
    for (int off = 1; off < 256; off <<= 1) {
        int t = (threadIdx.x >= off) ? sums[threadIdx.x - off] : 0;
        __syncthreads();
        sums[threadIdx.x] += t;
        __syncthreads();
    }
    int excl = sums[threadIdx.x] - s;
    if (threadIdx.x == 255) partials[blockIdx.x] = sums[255];
    int run = excl;
    #pragma unroll
    for (int i = 0; i < 4; ++i) {
        int idx = base + i;
        if (idx < N) { rowptr[idx] = run; cursor[idx] = run; }
        run += v[i];
    }
}

// ---------- scan step 2: exclusive-scan the block partials ----------
__global__ __launch_bounds__(256) void scan2(int* __restrict__ partials, int nb)
{
    __shared__ int s[256];
    int v = (threadIdx.x < nb) ? partials[threadIdx.x] : 0;
    s[threadIdx.x] = v;
    __syncthreads();
    for (int off = 1; off < 256; off <<= 1) {
        int t = (threadIdx.x >= off) ? s[threadIdx.x - off] : 0;
        __syncthreads();
        s[threadIdx.x] += t;
        __syncthreads();
    }
    partials[threadIdx.x] = s[threadIdx.x] - v;   // exclusive
}

// ---------- fill CSR with gated edges (block offset folded in) ----------
__global__ __launch_bounds__(256) void edge_fill(
    const int* __restrict__ ei, const float* __restrict__ alpha,
    int* __restrict__ cursor, const int* __restrict__ partials,
    int2* __restrict__ recs, int E)
{
    int e = blockIdx.x * 256 + threadIdx.x;
    if (e >= E) return;
    float gate = 2.0f * fmaxf(alpha[e] - 0.5f, 0.0f);
    if (gate > 0.0f) {
        int dst = ei[E + e];
        int src = ei[e];
        int pos = atomicAdd(&cursor[dst], 1) + partials[dst >> 10];
        recs[pos] = make_int2(src, __float_as_int(gate));
    }
}

// ---------- per-node gather + mean: one wave/node, 4 edges/iter ----------
__global__ __launch_bounds__(256) void node_gather(
    const unsigned short* __restrict__ h, const unsigned long long* __restrict__ deg,
    const int* __restrict__ rowptr, const int* __restrict__ partials,
    const int2* __restrict__ recs, float* __restrict__ out, int N)
{
    int wave = threadIdx.x >> 6;
    int lane = threadIdx.x & 63;
    int node = blockIdx.x * 4 + wave;
    if (node >= N) return;
    unsigned long long d = deg[node];
    int dAll  = __builtin_amdgcn_readfirstlane((int)(d >> 32));
    int dG    = __builtin_amdgcn_readfirstlane((int)(d & 0xffffffffULL));
    int start = __builtin_amdgcn_readfirstlane(rowptr[node] + partials[node >> 10]);
    int qw = lane >> 4, ql = lane & 15;     // quarter-wave per edge; 16 lanes x 16B = row
    float a[8] = {};
    for (int j = 0; j < dG; j += 4) {
        int jj = j + qw;
        int idx = start + (jj < dG ? jj : dG - 1);
        int2 rec = recs[idx];
        float gate = (jj < dG) ? __int_as_float(rec.y) : 0.0f;
        uint4 u = *(const uint4*)(h + ((size_t)rec.x << 7) + ql * 8);
        a[0] += bf2f((unsigned short)(u.x & 0xffffu)) * gate;
        a[1] += bf2f((unsigned short)(u.x >> 16)) * gate;
        a[2] += bf2f((unsigned short)(u.y & 0xffffu)) * gate;
        a[3] += bf2f((unsigned short)(u.y >> 16)) * gate;
        a[4] += bf2f((unsigned short)(u.z & 0xffffu)) * gate;
        a[5] += bf2f((unsigned short)(u.z >> 16)) * gate;
        a[6] += bf2f((unsigned short)(u.w & 0xffffu)) * gate;
        a[7] += bf2f((unsigned short)(u.w >> 16)) * gate;
    }
    #pragma unroll
    for (int i = 0; i < 8; ++i) {
        a[i] += __shfl_xor(a[i], 16);
        a[i] += __shfl_xor(a[i], 32);
    }
    if (qw == 0) {
        float inv = 1.0f / fmaxf((float)dAll, 1.0f);
        float* op = out + ((size_t)node << 7) + ql * 8;
        *(float4*)(op)     = make_float4(a[0] * inv, a[1] * inv, a[2] * inv, a[3] * inv);
        *(float4*)(op + 4) = make_float4(a[4] * inv, a[5] * inv, a[6] * inv, a[7] * inv);
    }
}

// ---------- launch ----------
extern "C" void kernel_launch(void* const* d_in, const int* in_sizes, int n_in,
                              void* d_out, int out_size, void* d_ws, size_t ws_size,
                              hipStream_t stream) {
    const float* x     = (const float*)d_in[0];
    const float* alpha = (const float*)d_in[1];
    const int*   ei    = (const int*)d_in[2];
    const float* W1 = (const float*)d_in[4];
    const float* b1 = (const float*)d_in[5];
    const float* W2 = (const float*)d_in[6];
    const float* b2 = (const float*)d_in[7];
    const float* W3 = (const float*)d_in[8];
    const float* b3 = (const float*)d_in[9];
    float* out = (float*)d_out;

    const int N = in_sizes[0] / 256;   // 100000
    const int E = in_sizes[1];         // 640000
    const int H1 = 512, D = 128;

    char* ws = (char*)d_ws;
    size_t off = 0;
    auto take = [&](size_t bytes) { char* p = ws + off; off = (off + bytes + 255) & ~(size_t)255; return p; };
    unsigned short* hbf  = (unsigned short*)take((size_t)N * D  * 2);
    unsigned short* w1bf = (unsigned short*)take((size_t)H1 * 256 * 2);
    unsigned short* w2bf = (unsigned short*)take((size_t)256 * H1 * 2);
    unsigned short* w3bf = (unsigned short*)take((size_t)D * 256 * 2);
    unsigned long long* deg = (unsigned long long*)take((size_t)N * 8);
    int*  rowptr   = (int*)take((size_t)N * 4);
    int*  cursor   = (int*)take((size_t)N * 4);
    int*  partials = (int*)take(256 * 4);
    int2* recs     = (int2*)take((size_t)E * 8);

    dim3 blk(256);

    // ---- fused MLP ----
    cast_w<<<288, blk, 0, stream>>>(W1, w1bf, W2, w2bf, W3, w3bf);
    mlp_fused<<<(N + 63) / 64, dim3(512), 0, stream>>>(
        x, w1bf, b1, w2bf, b2, w3bf, b3, hbf, N);

    // ---- CSR build ----
    hipMemsetAsync(deg, 0, (size_t)N * 8, stream);
    edge_hist<<<(E + 255) / 256, blk, 0, stream>>>(ei, alpha, deg, E);
    const int nb1 = (N + 1023) / 1024;   // 98
    scan1<<<nb1, blk, 0, stream>>>(deg, rowptr, cursor, partials, N);
    scan2<<<1, blk, 0, stream>>>(partials, nb1);
    edge_fill<<<(E + 255) / 256, blk, 0, stream>>>(ei, alpha, cursor, partials, recs, E);

    // ---- gather + mean ----
    node_gather<<<(N + 3) / 4, blk, 0, stream>>>(hbf, deg, rowptr, partials, recs, out, N);
}